// Round 9
// baseline (343.947 us; speedup 1.0000x reference)
//
#include <hip/hip_runtime.h>
#include <hip/hip_bf16.h>

typedef float f32x4 __attribute__((ext_vector_type(4)));
typedef __bf16 bf16x8 __attribute__((ext_vector_type(8)));
typedef unsigned short u16x8 __attribute__((ext_vector_type(8)));

#define GN_EPS 1e-5f
#define LN_EPS 1e-5f
#define COS_EPS_F 1e-8f

__device__ __forceinline__ unsigned short f2bf(float f) {
  unsigned int u = __builtin_bit_cast(unsigned int, f);
  u += 0x7fffu + ((u >> 16) & 1u);   // round-to-nearest-even
  return (unsigned short)(u >> 16);
}

// ---------------------------------------------------------------------------
// Coalesced transpose + bf16 cast: x[b][ci][hw] f32 -> xT(+m*stride)[b][hw][ci].
// ---------------------------------------------------------------------------
__global__ void transpose_kernel(const float* __restrict__ x0,
                                 const float* __restrict__ x1,
                                 const float* __restrict__ x2,
                                 unsigned short* __restrict__ xT,
                                 unsigned int strideElems, int mBase) {
  __shared__ float lds[64][129];
  int m = mBase + (blockIdx.x >> 11);
  int bid = blockIdx.x & 2047;          // b*8 + cit*4 + hwt
  const float* x = (m == 0) ? x0 : ((m == 1) ? x1 : x2);
  unsigned short* dst = xT + (unsigned int)(m - mBase) * strideElems;

  int hwt = bid & 3, cit = (bid >> 2) & 1, b = bid >> 3;
  int hw0 = hwt * 64, ci0 = cit * 128;
  int tid = threadIdx.x;

  int hwx = tid & 63, cy0 = tid >> 6;
  const float* xb = x + (b * 256 + ci0) * 256 + hw0;
  #pragma unroll 8
  for (int p = 0; p < 32; ++p) {
    int cy = cy0 + 4 * p;
    lds[hwx][cy] = xb[cy * 256 + hwx];
  }
  __syncthreads();

  int cp = tid & 63, hy0 = tid >> 6;
  unsigned int* outp = (unsigned int*)(dst + (b * 256 + hw0) * 256 + ci0);
  #pragma unroll 4
  for (int p = 0; p < 16; ++p) {
    int hy = hy0 + 4 * p;
    float lo = lds[hy][2 * cp];
    float hi = lds[hy][2 * cp + 1];
    unsigned int w = ((unsigned int)f2bf(hi) << 16) | f2bf(lo);
    outp[hy * 128 + cp] = w;
  }
}

// ---------------------------------------------------------------------------
// Repack conv weights (all 3): W[co][ci][3][3] f32 -> wp[m][co][9][ci] bf16
// ---------------------------------------------------------------------------
__global__ void pack_kernel(const float* __restrict__ w0,
                            const float* __restrict__ w1,
                            const float* __restrict__ w2,
                            unsigned short* __restrict__ wp) {
  int m = blockIdx.y;
  const float* w = (m == 0) ? w0 : ((m == 1) ? w1 : w2);
  int idx = blockIdx.x * 256 + threadIdx.x;   // 0..589823
  int ci = idx & 255;
  int rest = idx >> 8;
  int khw = rest % 9, co = rest / 9;
  wp[m * 589824 + idx] = f2bf(w[(co * 256 + ci) * 9 + khw]);
}

// ---------------------------------------------------------------------------
// Fused Conv3x3 + bias + GroupNorm(16) + ReLU + spatial mean.
// Block = 2 images x 128 co (M=512, N=128), 512 threads, 8 waves (4M x 2N),
// wave tile 128x64, acc[8][4].
// A-REUSE dataflow: per ci-block kc, the WHOLE 2-image slice (2x256px x 32ci
// = 32 KB) is staged ONCE; all 9 taps read it from LDS with shifted
// per-frag addresses (invalid border lanes read a zeroed 64B block).
// A staged 1x instead of 9x -> total staged bytes 1.73 GB -> 0.63 GB.
// B: [128co x 32ci] = 8 KB per (kc,tap), triple-buffered, staged 2 tiles
// ahead, counted vmcnt (1, or 5 on A-stage tiles; 0 only in tail).
// A: double-buffered across kc (staged at tap 0 of previous kc).
// Frag reads are naturally bank-conflict-free: granule (q*4+l4) mod 8.
// ---------------------------------------------------------------------------
__device__ __forceinline__ void gl_lds16(const unsigned short* g, unsigned short* l) {
  __builtin_amdgcn_global_load_lds(
      (const __attribute__((address_space(1))) void*)g,
      (__attribute__((address_space(3))) void*)l, 16, 0, 0);
}

__launch_bounds__(512, 2)
__global__ void conv_gn_pool(const unsigned short* __restrict__ xT,
                             unsigned int xTstride,
                             const unsigned short* __restrict__ wp,
                             const float* __restrict__ cb0, const float* __restrict__ cb1,
                             const float* __restrict__ cb2,
                             const float* __restrict__ gg0, const float* __restrict__ gg1,
                             const float* __restrict__ gg2,
                             const float* __restrict__ gb0, const float* __restrict__ gb1,
                             const float* __restrict__ gb2,
                             float* __restrict__ enc, int mBase, int chunk) {
  __shared__ unsigned short As[2][16384];  // 64 KB: 2 bufs x (2 img x 256 px x 32 ci)
  __shared__ unsigned short Bb[3][4096];   // 24 KB: 3 bufs x (128 co x 32 ci)
  __shared__ unsigned short zbuf[32];      // 64 B zero block for border reads
  __shared__ float gsum[16], gsq[16], pooled[256];

  int bid = blockIdx.x;
  // XCD-aware decode: xcd = bid&7 (HW round-robin), pairs of co-halves and
  // images of the same m cluster on one XCD -> L2-resident weights + shared A.
  int xcd = bid & 7, kk = bid >> 3;
  int nt = kk & 1;
  int pg = xcd * chunk + (kk >> 1);        // pair-global 0..(3*128 or 128)-1
  int mm = mBase + (pg >> 7);
  int pr = pg & 127;                       // image pair within m

  const float* cbias = (mm == 0) ? cb0 : ((mm == 1) ? cb1 : cb2);
  const float* gng   = (mm == 0) ? gg0 : ((mm == 1) ? gg1 : gg2);
  const float* gnb   = (mm == 0) ? gb0 : ((mm == 1) ? gb1 : gb2);

  int tid = threadIdx.x;
  int wid = tid >> 6, lane = tid & 63;
  int wr = wid >> 1, wc = wid & 1;         // wave grid 4(M) x 2(N)
  int l15 = lane & 15, l4 = lane >> 4;

  if (tid < 16) { gsum[tid] = 0.f; gsq[tid] = 0.f; }
  if (tid < 256) pooled[tid] = 0.f;
  if (tid < 32) zbuf[tid] = 0;

  // ---- global bases ----
  const unsigned short* xbPair =
      xT + (unsigned int)(mm - mBase) * xTstride + (unsigned int)(pr * 2) * 65536u;
  const unsigned short* wpB = wp + mm * 589824 + (nt * 128) * 2304;

  // ---- staging decode (compile-time-friendly) ----
  int sco = tid >> 2, sk4 = tid & 3;       // B: thread -> (co, ci-chunk)

  // ---- per-frag A read precompute ----
  int hh8[8], ww8[8], bq8[8];
  #pragma unroll
  for (int mf = 0; mf < 8; ++mf) {
    int r = wr * 128 + mf * 16 + l15;      // output row 0..511
    int img = r >> 8, p = r & 255;
    hh8[mf] = p >> 4; ww8[mf] = p & 15;
    bq8[mf] = img * 8192 + p * 32 + l4 * 8;
  }
  int bq4[4];
  #pragma unroll
  for (int nf = 0; nf < 4; ++nf)
    bq4[nf] = (wc * 64 + nf * 16 + l15) * 32 + l4 * 8;

  f32x4 acc[8][4];
  #pragma unroll
  for (int i = 0; i < 8; ++i)
    #pragma unroll
    for (int j = 0; j < 4; ++j) acc[i][j] = (f32x4)(0.0f);

  #define LD8(P) __builtin_bit_cast(bf16x8, *(const u16x8*)(P))

  // Stage the 32 KB A-slice for ci-block KCN into As[PAR] (4 loads/thread)
  #define STAGE_A(KCN, PAR)                                                    \
    {                                                                          \
      unsigned short* dstA = &As[(PAR)][0];                                    \
      _Pragma("unroll")                                                        \
      for (int j = 0; j < 4; ++j) {                                            \
        int c = tid + j * 512;                                                 \
        int img_ = c >> 10, p_ = (c >> 2) & 255, k4_ = c & 3;                  \
        gl_lds16(xbPair + img_ * 65536 + p_ * 256 + (KCN) * 32 + k4_ * 8,      \
                 dstA + c * 8);                                                \
      }                                                                        \
    }
  // Stage the 8 KB B-tile (KC2, TAP2) into Bb[BUF2] (1 load/thread)
  #define STAGE_B(KC2, TAP2, BUF2)                                             \
    gl_lds16(wpB + sco * 2304 + (TAP2) * 256 + (KC2) * 32 + sk4 * 8,           \
             &Bb[(BUF2)][tid * 8]);

  // One tap-tile: DH,DW,TAP compile-time; kc from scope. DO_A: stage A(kc+1).
  // DO_B: stage B(KC2,TAP2). VMN: vmcnt literal.
  #define TAP_BODY(TAP, DH, DW, DO_A, DO_B, KC2, TAP2, VMN)                    \
    {                                                                          \
      if (DO_A) STAGE_A(kc + 1, (kc + 1) & 1);                                 \
      if (DO_B) STAGE_B(KC2, TAP2, ((TAP) + 2) % 3);                           \
      const unsigned short* AsC = &As[kc & 1][0];                              \
      bf16x8 af[8], bfr[4];                                                    \
      _Pragma("unroll")                                                        \
      for (int nf = 0; nf < 4; ++nf)                                           \
        bfr[nf] = LD8(&Bb[(TAP) % 3][bq4[nf]]);                                \
      _Pragma("unroll")                                                        \
      for (int mf = 0; mf < 8; ++mf) {                                         \
        int ok = 1;                                                            \
        if ((DH) == 0) ok &= (hh8[mf] >= 1);                                   \
        if ((DH) == 2) ok &= (hh8[mf] <= 14);                                  \
        if ((DW) == 0) ok &= (ww8[mf] >= 1);                                   \
        if ((DW) == 2) ok &= (ww8[mf] <= 14);                                  \
        const unsigned short* pa =                                             \
            ok ? AsC + (bq8[mf] + (((DH) * 16 + (DW)) - 17) * 32)              \
               : &zbuf[l4 * 8];                                                \
        af[mf] = LD8(pa);                                                      \
      }                                                                        \
      __builtin_amdgcn_s_barrier();                                            \
      asm volatile("s_waitcnt lgkmcnt(0)" ::: "memory");                       \
      __builtin_amdgcn_sched_barrier(0);                                       \
      __builtin_amdgcn_s_setprio(1);                                           \
      _Pragma("unroll")                                                        \
      for (int mf = 0; mf < 8; ++mf)                                           \
        _Pragma("unroll")                                                      \
        for (int nf = 0; nf < 4; ++nf)                                         \
          acc[mf][nf] = __builtin_amdgcn_mfma_f32_16x16x32_bf16(               \
              af[mf], bfr[nf], acc[mf][nf], 0, 0, 0);                          \
      __builtin_amdgcn_s_setprio(0);                                           \
      asm volatile("s_waitcnt vmcnt(" #VMN ")" ::: "memory");                  \
      __builtin_amdgcn_s_barrier();                                            \
    }

  // ---- prologue: A(0), B(0,0), B(0,1) ----
  {
    int kc = 0; (void)kc;
    STAGE_A(0, 0);
    STAGE_B(0, 0, 0);
    STAGE_B(0, 1, 1);
    asm volatile("s_waitcnt vmcnt(1)" ::: "memory");   // A0 + B(0,0) landed
    __builtin_amdgcn_s_barrier();
  }

  // ---- main: kc = 0..6 ----
  for (int kc = 0; kc < 7; ++kc) {
    TAP_BODY(0, 0, 0, 1, 1, kc, 2, 5)
    TAP_BODY(1, 0, 1, 0, 1, kc, 3, 1)
    TAP_BODY(2, 0, 2, 0, 1, kc, 4, 1)
    TAP_BODY(3, 1, 0, 0, 1, kc, 5, 1)
    TAP_BODY(4, 1, 1, 0, 1, kc, 6, 1)
    TAP_BODY(5, 1, 2, 0, 1, kc, 7, 1)
    TAP_BODY(6, 2, 0, 0, 1, kc, 8, 1)
    TAP_BODY(7, 2, 1, 0, 1, kc + 1, 0, 1)
    TAP_BODY(8, 2, 2, 0, 1, kc + 1, 1, 1)
  }
  // ---- tail: kc = 7 (no A-stage; B stops at t=70) ----
  {
    const int kc = 7;
    TAP_BODY(0, 0, 0, 0, 1, 7, 2, 1)
    TAP_BODY(1, 0, 1, 0, 1, 7, 3, 1)
    TAP_BODY(2, 0, 2, 0, 1, 7, 4, 1)
    TAP_BODY(3, 1, 0, 0, 1, 7, 5, 1)
    TAP_BODY(4, 1, 1, 0, 1, 7, 6, 1)
    TAP_BODY(5, 1, 2, 0, 1, 7, 7, 1)
    TAP_BODY(6, 2, 0, 0, 1, 7, 8, 1)
    TAP_BODY(7, 2, 1, 0, 0, 7, 0, 0)
    TAP_BODY(8, 2, 2, 0, 0, 7, 0, 0)
  }
  #undef TAP_BODY
  #undef STAGE_A
  #undef STAGE_B
  #undef LD8

  __syncthreads();

  // ---- epilogue: +bias, per-image group stats (8 groups per co-half) ----
  int img = wr >> 1;                       // wave-uniform image index
  float bias[4], ggv[4], gbv[4];
  #pragma unroll
  for (int nf = 0; nf < 4; ++nf) {
    int co = nt * 128 + wc * 64 + nf * 16 + l15;
    bias[nf] = cbias[co]; ggv[nf] = gng[co]; gbv[nf] = gnb[co];
  }
  #pragma unroll
  for (int nf = 0; nf < 4; ++nf) {
    float s1 = 0.f, s2 = 0.f;
    #pragma unroll
    for (int mf = 0; mf < 8; ++mf)
      #pragma unroll
      for (int i = 0; i < 4; ++i) {
        float v = acc[mf][nf][i] + bias[nf];
        acc[mf][nf][i] = v;
        s1 += v; s2 += v * v;
      }
    #pragma unroll
    for (int d = 1; d < 64; d <<= 1) {
      s1 += __shfl_xor(s1, d);
      s2 += __shfl_xor(s2, d);
    }
    if (lane == 0) {
      atomicAdd(&gsum[img * 8 + wc * 4 + nf], s1);
      atomicAdd(&gsq[img * 8 + wc * 4 + nf], s2);
    }
  }
  __syncthreads();
  // ---- normalize + relu + pool ----
  #pragma unroll
  for (int nf = 0; nf < 4; ++nf) {
    int g = img * 8 + wc * 4 + nf;
    float mean = gsum[g] * (1.f / 4096.f);
    float var = gsq[g] * (1.f / 4096.f) - mean * mean;
    float rs = rsqrtf(var + GN_EPS);
    float p = 0.f;
    #pragma unroll
    for (int mf = 0; mf < 8; ++mf)
      #pragma unroll
      for (int i = 0; i < 4; ++i) {
        float v = (acc[mf][nf][i] - mean) * rs * ggv[nf] + gbv[nf];
        p += fmaxf(v, 0.f);
      }
    p += __shfl_xor(p, 16);
    p += __shfl_xor(p, 32);
    if (lane < 16) atomicAdd(&pooled[img * 128 + wc * 64 + nf * 16 + l15], p);
  }
  __syncthreads();
  if (tid < 256) {
    int oimg = tid >> 7, ch = tid & 127;
    enc[mm * 65536 + (pr * 2 + oimg) * 256 + nt * 128 + ch] =
        pooled[tid] * (1.f / 256.f);
  }
}

// ---------------------------------------------------------------------------
// Projector + LN + l2norm + predictor. One block per row (768 rows).
// ---------------------------------------------------------------------------
__global__ void proj_pred(const float* __restrict__ enc,
                          const float* __restrict__ w1, const float* __restrict__ b1,
                          const float* __restrict__ w2, const float* __restrict__ b2,
                          const float* __restrict__ lng, const float* __restrict__ lnb,
                          const float* __restrict__ pw1, const float* __restrict__ pb1,
                          const float* __restrict__ pw2, const float* __restrict__ pb2,
                          float* __restrict__ proj, float* __restrict__ pred,
                          float* __restrict__ znorm) {
  __shared__ float row[256], h1[256], zz[128], p1[128], red[2];
  int r = blockIdx.x, tid = threadIdx.x;
  row[tid] = enc[r * 256 + tid];
  __syncthreads();
  float a = 0.f;
  for (int k = 0; k < 256; ++k) a += row[k] * w1[k * 256 + tid];
  h1[tid] = fmaxf(a + b1[tid], 0.f);
  __syncthreads();
  if (tid < 128) {
    a = 0.f;
    for (int k = 0; k < 256; ++k) a += h1[k] * w2[k * 128 + tid];
    zz[tid] = a + b2[tid];
  }
  __syncthreads();
  if (tid == 0) {
    float m = 0.f;
    for (int k = 0; k < 128; ++k) m += zz[k];
    m *= (1.f / 128.f);
    float v = 0.f;
    for (int k = 0; k < 128; ++k) { float d = zz[k] - m; v += d * d; }
    red[0] = m;
    red[1] = rsqrtf(v * (1.f / 128.f) + LN_EPS);
  }
  __syncthreads();
  float zval = 0.f;
  if (tid < 128) {
    zval = (zz[tid] - red[0]) * red[1] * lng[tid] + lnb[tid];
    proj[r * 128 + tid] = zval;
  }
  __syncthreads();
  if (tid < 128) zz[tid] = zval;     // zz now holds LN output
  __syncthreads();
  if (tid == 0) {
    float s = 0.f;
    for (int k = 0; k < 128; ++k) s += zz[k] * zz[k];
    red[0] = 1.f / fmaxf(sqrtf(s), COS_EPS_F);
  }
  __syncthreads();
  if (tid < 128) {
    znorm[r * 128 + tid] = zz[tid] * red[0];
    a = 0.f;
    for (int k = 0; k < 128; ++k) a += zz[k] * pw1[k * 128 + tid];
    p1[tid] = fmaxf(a + pb1[tid], 0.f);
  }
  __syncthreads();
  if (tid < 128) {
    a = 0.f;
    for (int k = 0; k < 128; ++k) a += p1[k] * pw2[k * 128 + tid];
    pred[r * 128 + tid] = a + pb2[tid];
  }
}

// ---------------------------------------------------------------------------
// Loss: block = (pair, k). lse(S[k,:]) - S[k,k] per row; partials to ws.
// ---------------------------------------------------------------------------
__global__ void loss_kernel(const float* __restrict__ zn, float* __restrict__ part) {
  __shared__ float zi[128], sv[256], rbuf[256];
  int blk = blockIdx.x;           // p*256 + k
  int p = blk >> 8, k = blk & 255;
  int i = (p == 2) ? 1 : 0;
  int j = (p == 0) ? 1 : 2;
  int tid = threadIdx.x;
  if (tid < 128) zi[tid] = zn[(i * 256 + k) * 128 + tid];
  __syncthreads();
  const float4* zj = (const float4*)&zn[(j * 256 + tid) * 128];
  float s = 0.f;
  #pragma unroll 8
  for (int d = 0; d < 32; ++d) {
    float4 aq = *(const float4*)&zi[d * 4];
    float4 bq = zj[d];
    s += aq.x * bq.x + aq.y * bq.y + aq.z * bq.z + aq.w * bq.w;
  }
  s *= 10.0f;                      // 1/TEMP
  sv[tid] = s;
  rbuf[tid] = s;
  __syncthreads();
  for (int d = 128; d > 0; d >>= 1) {
    if (tid < d) rbuf[tid] = fmaxf(rbuf[tid], rbuf[tid + d]);
    __syncthreads();
  }
  float m = rbuf[0];
  __syncthreads();
  rbuf[tid] = expf(s - m);
  __syncthreads();
  for (int d = 128; d > 0; d >>= 1) {
    if (tid < d) rbuf[tid] += rbuf[tid + d];
    __syncthreads();
  }
  if (tid == 0) part[blk] = m + logf(rbuf[0]) - sv[k];
}

__global__ void finalize_loss(const float* __restrict__ part, float* __restrict__ out) {
  __shared__ float red[256];
  int tid = threadIdx.x;
  float s = 0.f;
  for (int idx = tid; idx < 768; idx += 256) s += part[idx];
  red[tid] = s;
  __syncthreads();
  for (int d = 128; d > 0; d >>= 1) {
    if (tid < d) red[tid] += red[tid + d];
    __syncthreads();
  }
  if (tid == 0) out[0] = red[0] * (1.f / 768.f);
}

// ---------------------------------------------------------------------------
extern "C" void kernel_launch(void* const* d_in, const int* in_sizes, int n_in,
                              void* d_out, int out_size, void* d_ws, size_t ws_size,
                              hipStream_t stream) {
  const float* x[3]  = {(const float*)d_in[0], (const float*)d_in[1], (const float*)d_in[2]};
  const float* cw[3] = {(const float*)d_in[3], (const float*)d_in[7], (const float*)d_in[11]};
  const float* cb[3] = {(const float*)d_in[4], (const float*)d_in[8], (const float*)d_in[12]};
  const float* gg[3] = {(const float*)d_in[5], (const float*)d_in[9], (const float*)d_in[13]};
  const float* gb[3] = {(const float*)d_in[6], (const float*)d_in[10], (const float*)d_in[14]};
  const float* p_w1 = (const float*)d_in[15];
  const float* p_b1 = (const float*)d_in[16];
  const float* p_w2 = (const float*)d_in[17];
  const float* p_b2 = (const float*)d_in[18];
  const float* ln_g = (const float*)d_in[19];
  const float* ln_b = (const float*)d_in[20];
  const float* q_w1 = (const float*)d_in[21];
  const float* q_b1 = (const float*)d_in[22];
  const float* q_w2 = (const float*)d_in[23];
  const float* q_b2 = (const float*)d_in[24];

  float* out = (float*)d_out;
  char* ws = (char*)d_ws;

  const size_t XT_ONE = 33554432;        // bytes per image-set xT
  bool merged = ws_size >= (3 * XT_ONE + 3538944 + 393216 + 3072 + 512);

  size_t xt_total = merged ? 3 * XT_ONE : XT_ONE;
  unsigned short* xT  = (unsigned short*)ws;
  unsigned short* wpk = (unsigned short*)(ws + xt_total);             // 3,538,944 B (3 sets)
  float* znorm = (float*)(ws + xt_total + 3538944);                   //   393,216 B
  float* part  = (float*)(ws + xt_total + 3538944 + 393216);          //     3,072 B

  float* enc  = out;              // [3][256][256]
  float* proj = out + 196608;     // [3][256][128]
  float* pred = out + 294912;     // [3][256][128]
  float* lossp = out + 393216;    // scalar

  pack_kernel<<<dim3(2304, 3), dim3(256), 0, stream>>>(cw[0], cw[1], cw[2], wpk);

  if (merged) {
    transpose_kernel<<<dim3(6144), dim3(256), 0, stream>>>(x[0], x[1], x[2], xT, 16777216u, 0);
    conv_gn_pool<<<dim3(768), dim3(512), 0, stream>>>(
        xT, 16777216u, wpk, cb[0], cb[1], cb[2], gg[0], gg[1], gg[2],
        gb[0], gb[1], gb[2], enc, 0, 48);
  } else {
    for (int m = 0; m < 3; ++m) {
      transpose_kernel<<<dim3(2048), dim3(256), 0, stream>>>(x[0], x[1], x[2], xT, 0u, m);
      conv_gn_pool<<<dim3(256), dim3(512), 0, stream>>>(
          xT, 0u, wpk, cb[0], cb[1], cb[2], gg[0], gg[1], gg[2],
          gb[0], gb[1], gb[2], enc, m, 16);
    }
  }
  proj_pred<<<dim3(768), dim3(256), 0, stream>>>(enc, p_w1, p_b1, p_w2, p_b2, ln_g, ln_b,
                                                 q_w1, q_b1, q_w2, q_b2, proj, pred, znorm);
  loss_kernel<<<dim3(768), dim3(256), 0, stream>>>(znorm, part);
  finalize_loss<<<dim3(1), dim3(256), 0, stream>>>(part, lossp);
}